// Round 9
// baseline (5679.467 us; speedup 1.0000x reference)
//
#include <hip/hip_runtime.h>
#include <hip/hip_bf16.h>

#define LAT 128
#define H 256
#define OUTD 64
#define SEQ 512

typedef short bf16x8 __attribute__((ext_vector_type(8)));
typedef float f32x4  __attribute__((ext_vector_type(4)));
typedef unsigned long long u64;
typedef unsigned u32;

__device__ __forceinline__ float sigm(float x)  { return 1.f / (1.f + __expf(-x)); }
__device__ __forceinline__ float tanhf_(float x){ return 1.f - 2.f / (__expf(2.f * x) + 1.f); }

__device__ __forceinline__ short f2bs(float x) {
    __hip_bfloat16 b = __float2bfloat16(x);
    return *reinterpret_cast<short*>(&b);
}
__device__ __forceinline__ float bs2f(unsigned short h) {
    u32 b = ((u32)h) << 16;
    float f; __builtin_memcpy(&f, &b, 4); return f;
}
__device__ __forceinline__ u32 f2pair(float a, float b) {
    return ((u32)(unsigned short)f2bs(b) << 16) | (u32)(unsigned short)f2bs(a);
}
__device__ __forceinline__ bf16x8 pack8(const float* s) {
    bf16x8 v;
    v[0]=f2bs(s[0]); v[1]=f2bs(s[1]); v[2]=f2bs(s[2]); v[3]=f2bs(s[3]);
    v[4]=f2bs(s[4]); v[5]=f2bs(s[5]); v[6]=f2bs(s[6]); v[7]=f2bs(s[7]);
    return v;
}

// ---- LLC-coherent accessors (round-5/8-proven transport) ----
__device__ __forceinline__ u32 sys_load_u32(const u32* p) {
    return __hip_atomic_load((u32*)p, __ATOMIC_RELAXED, __HIP_MEMORY_SCOPE_SYSTEM);
}
__device__ __forceinline__ void sys_store_u32(u32* p, u32 v) {
    __hip_atomic_store(p, v, __ATOMIC_RELAXED, __HIP_MEMORY_SCOPE_SYSTEM);
}

// ---------------- Prologue 1: tagged h-init (col-major u32 slots), c-init, L1 bias ----
// Slot: u32 = (tag16 << 16) | bf16. Slot index within cluster: col*16 + (b&15).
// h0 init -> hA1 tag 0 (polled at iter 0); h1 init -> hB1 tag 1 (iter 1).
__global__ void lstm_prologue_init(const float* __restrict__ z,
                                   const float* __restrict__ Whid,
                                   const float* __restrict__ bhid,
                                   const float* __restrict__ Wcell,
                                   const float* __restrict__ bcell,
                                   const float* __restrict__ bih1,
                                   const float* __restrict__ bhh1,
                                   u32* __restrict__ hA1,
                                   u32* __restrict__ hB1,
                                   float* __restrict__ c0,
                                   float* __restrict__ c1,
                                   float* __restrict__ gxb1)
{
    int t = blockIdx.x * 256 + threadIdx.x;
    if (t < 131072) {                    // tagged hidden init: 2 layers x 256 b x 256 cols
        int layer = t >> 16;
        int rem = t & 65535;
        int b = rem & 255, col = rem >> 8;
        int wrow = layer * H + col;
        const float* w  = Whid + wrow * LAT;
        const float* zr = z + b * LAT;
        float acc = bhid[wrow];
        for (int k = 0; k < LAT; k++) acc += zr[k] * w[k];
        u32 slot = ((u32)layer << 16) | (u32)(unsigned short)f2bs(acc);
        (layer ? hB1 : hA1)[(b >> 4) * 4096 + col * 16 + (b & 15)] = slot;
    } else if (t < 262144) {             // cell init: 2 layers x 256 b x 256 cols
        int rem = t - 131072;
        int layer = rem >> 16;
        int r2 = rem & 65535;
        int b = r2 & 255, col = r2 >> 8;
        int wrow = layer * H + col;
        const float* w  = Wcell + wrow * LAT;
        const float* zr = z + b * LAT;
        float acc = bcell[wrow];
        for (int k = 0; k < LAT; k++) acc += zr[k] * w[k];
        (layer ? c1 : c0)[b * H + col] = acc;
    } else if (t < 263168) {             // layer-1 gate bias vector [1024]
        int g = t - 262144;
        gxb1[g] = bih1[g] + bhh1[g];
    }
}

// ---------------- Prologue 2: gx0 = (z@Win.T+bin) @ W_ih0.T + biases, bf16 pairs ----
__global__ void lstm_prologue_gx0(const float* __restrict__ z,
                                  const float* __restrict__ Win,
                                  const float* __restrict__ bin,
                                  const float* __restrict__ Wih0,
                                  const float* __restrict__ bih0,
                                  const float* __restrict__ bhh0,
                                  u32* __restrict__ gxb0u)
{
    __shared__ float xs[H];
    const int b = blockIdx.y;
    const int tid = threadIdx.x;
    {
        const float* w  = Win + tid * LAT;
        const float* zr = z + b * LAT;
        float acc = bin[tid];
        for (int k = 0; k < LAT; k++) acc += zr[k] * w[k];
        xs[tid] = acc;
    }
    __syncthreads();
    const int cA = blockIdx.x * 512 + 2 * tid;
    const float* wA = Wih0 + cA * H;
    const float* wB = wA + H;
    float a0 = bih0[cA]     + bhh0[cA];
    float a1 = bih0[cA + 1] + bhh0[cA + 1];
    for (int k = 0; k < H; k++) { float xv = xs[k]; a0 += xv * wA[k]; a1 += xv * wB[k]; }
    gxb0u[b * 512 + blockIdx.x * 256 + tid] = f2pair(a0, a1);
}

// ---------------- Persistent kernel ----------------
// 256 wgs x 256 thr. Cluster bg = wg>>4 (batch rows 16bg..), wg j = wg&15 owns
// 16 hidden cols. MFMA transposed: A = weight rows packed m = c*4+g, B = h rows
// => C lane (q, ln): acc[r] = gate r of (batch ln, col j*16+wave*4+q). Nonlin on
// regs, publish tagged u32 (tag16|bf16) col-major (64B-line coalesced), one
// barrier/step (parity-double-buffered staging LDS). Tag at iter k: poll ==k,
// publish k+1. Same two-buffer ping-pong + tag protocol proven in round 8.
__global__ __launch_bounds__(256, 1)
void lstm_persistent(const u32* __restrict__ gxb0u, const float* __restrict__ gxb1,
                     const float* __restrict__ c0g, const float* __restrict__ c1g,
                     u32* __restrict__ hA0, u32* __restrict__ hA1,
                     u32* __restrict__ hB0, u32* __restrict__ hB1,
                     const float* __restrict__ Whh0, const float* __restrict__ Wih1,
                     const float* __restrict__ Whh1, const float* __restrict__ Wout,
                     const float* __restrict__ bout, float* __restrict__ out)
{
    const int wg = blockIdx.x;
    const int bg = wg >> 4;
    const int j  = wg & 15;
    const int tid  = threadIdx.x;
    const int wave = tid >> 6;
    const int lane = tid & 63;
    const int q  = lane >> 4;
    const int ln = lane & 15;
    const int mycol = j * 16 + wave * 4 + q;   // this lane's output hidden col
    const int myb   = bg * 16 + ln;            // this lane's output batch row

    // parity x layer staging planes, row-major packed col-pairs, +16 u32 pad
    __shared__ __align__(16) u32 hs[2][2][16 * 132 + 16];

    // ---- A-frags: packed-gate weight rows. lane ln: c = ln>>2, g = ln&3 ----
    bf16x8 wf[3][8];
    {
        const float* mats[3] = { Whh0, Wih1, Whh1 };
        const int arow = (ln & 3) * H + j * 16 + wave * 4 + (ln >> 2);
        #pragma unroll
        for (int mm = 0; mm < 3; mm++) {
            const float* s = mats[mm] + arow * H + q * 8;
            #pragma unroll
            for (int kk = 0; kk < 8; kk++) wf[mm][kk] = pack8(s + kk * 32);
        }
    }
    const bool doOut = (j == 0);               // one wg per cluster does out-proj
    bf16x8 wo[8];
    float bor[4] = {0.f, 0.f, 0.f, 0.f};
    if (doOut) {
        const int orow = wave * 16 + ln;       // natural rows for out (no gate packing)
        const float* s = Wout + orow * H + q * 8;
        #pragma unroll
        for (int kk = 0; kk < 8; kk++) wo[kk] = pack8(s + kk * 32);
        #pragma unroll
        for (int r = 0; r < 4; r++) bor[r] = bout[wave * 16 + q * 4 + r];
    }

    // ---- per-lane gate biases + cell state ----
    float gxr0[4], gxr1[4];
    #pragma unroll
    for (int r = 0; r < 4; r++) {
        u32 v = gxb0u[myb * 512 + ((r * 256 + mycol) >> 1)];
        gxr0[r] = bs2f((unsigned short)((mycol & 1) ? (v >> 16) : (v & 0xFFFFu)));
        gxr1[r] = gxb1[r * 256 + mycol];
    }
    float creg0 = c0g[myb * H + mycol];
    float creg1 = c1g[myb * H + mycol];

    // staging role: thread stages 2 cols x 16 rows of one layer
    const int sl  = tid >> 7;                  // layer
    const int scp = tid & 127;                 // col pair

    u32* A0 = hA0 + bg * 4096; u32* A1 = hA1 + bg * 4096;
    u32* B0 = hB0 + bg * 4096; u32* B1 = hB1 + bg * 4096;

    for (int k = 0; k <= SEQ + 1; k++) {
        const u32* P0 = (k & 1) ? A0 : A1;  u32* C0 = (k & 1) ? A1 : A0;
        const u32* P1 = (k & 1) ? B1 : B0;  u32* C1 = (k & 1) ? B0 : B1;
        const int par = k & 1;

        // ---- poll + stage (the poll IS the synchronization) ----
        {
            const bool act = sl ? (k >= 1) : (k <= SEQ);
            if (act) {
                const u32* src = (sl ? P1 : P0) + scp * 32;   // cols 2scp,2scp+1 x 16 rows
                u32 v[32];
                u32 pend = 0xFFFFFFFFu;
                #pragma unroll
                for (int i = 0; i < 32; i++) v[i] = sys_load_u32(src + i);
                int guard = 0;
                while (pend) {
                    u32 np = 0u;
                    #pragma unroll
                    for (int i = 0; i < 32; i++) {
                        if ((pend >> i) & 1u) {
                            if ((v[i] >> 16) != (u32)k) { v[i] = sys_load_u32(src + i); np |= 1u << i; }
                        }
                    }
                    pend = np;
                    if (++guard > 16384) break;    // fail visibly, never hang
                }
                u32* dst = &hs[par][sl][0];
                #pragma unroll
                for (int n = 0; n < 16; n++)
                    dst[n * 132 + scp] = (v[n] & 0xFFFFu) | ((v[16 + n] & 0xFFFFu) << 16);
            }
        }
        __syncthreads();                       // the ONLY barrier per step

        // ---- B-frags (h rows; B lane = batch row ln) ----
        bf16x8 hb0[8], hb1[8];
        const unsigned short* b0p = (const unsigned short*)&hs[par][0][0];
        const unsigned short* b1p = (const unsigned short*)&hs[par][1][0];
        #pragma unroll
        for (int kk = 0; kk < 8; kk++) {
            hb0[kk] = *(const bf16x8*)(b0p + ln * 264 + kk * 32 + q * 8);
            hb1[kk] = *(const bf16x8*)(b1p + ln * 264 + kk * 32 + q * 8);
        }

        // ---- layer 0, step k: gates land in acc[0..3] per lane ----
        if (k < SEQ) {
            f32x4 acc = {0.f, 0.f, 0.f, 0.f};
            #pragma unroll
            for (int kk = 0; kk < 8; kk++)
                acc = __builtin_amdgcn_mfma_f32_16x16x32_bf16(wf[0][kk], hb0[kk], acc, 0, 0, 0);
            float i_ = sigm(acc[0] + gxr0[0]);
            float f_ = sigm(acc[1] + gxr0[1]);
            float g_ = tanhf_(acc[2] + gxr0[2]);
            float o_ = sigm(acc[3] + gxr0[3]);
            creg0 = f_ * creg0 + i_ * g_;
            float h = o_ * tanhf_(creg0);
            sys_store_u32(C0 + mycol * 16 + ln,
                          ((u32)(k + 1) << 16) | (u32)(unsigned short)f2bs(h));
        }

        // ---- layer 1, step k-1 ----
        if (k >= 1 && k <= SEQ) {
            f32x4 acc = {0.f, 0.f, 0.f, 0.f};
            #pragma unroll
            for (int kk = 0; kk < 8; kk++)
                acc = __builtin_amdgcn_mfma_f32_16x16x32_bf16(wf[1][kk], hb0[kk], acc, 0, 0, 0);
            #pragma unroll
            for (int kk = 0; kk < 8; kk++)
                acc = __builtin_amdgcn_mfma_f32_16x16x32_bf16(wf[2][kk], hb1[kk], acc, 0, 0, 0);
            float i_ = sigm(acc[0] + gxr1[0]);
            float f_ = sigm(acc[1] + gxr1[1]);
            float g_ = tanhf_(acc[2] + gxr1[2]);
            float o_ = sigm(acc[3] + gxr1[3]);
            creg1 = f_ * creg1 + i_ * g_;
            float h = o_ * tanhf_(creg1);
            sys_store_u32(C1 + mycol * 16 + ln,
                          ((u32)(k + 1) << 16) | (u32)(unsigned short)f2bs(h));
        }

        // ---- output projection, step k-2 (wg0 only; reuses hb1 = h1_{k-2}) ----
        if (k >= 2 && doOut) {
            f32x4 acc = {0.f, 0.f, 0.f, 0.f};
            #pragma unroll
            for (int kk = 0; kk < 8; kk++)
                acc = __builtin_amdgcn_mfma_f32_16x16x32_bf16(wo[kk], hb1[kk], acc, 0, 0, 0);
            f32x4 res;
            #pragma unroll
            for (int r = 0; r < 4; r++) res[r] = acc[r] + bor[r];
            *(f32x4*)&out[(bg * 16 + ln) * (SEQ * OUTD) + (k - 2) * OUTD + wave * 16 + q * 4] = res;
        }
    }
}

extern "C" void kernel_launch(void* const* d_in, const int* in_sizes, int n_in,
                              void* d_out, int out_size, void* d_ws, size_t ws_size,
                              hipStream_t stream) {
    const float* z     = (const float*)d_in[0];
    const float* Whid  = (const float*)d_in[1];
    const float* bhid  = (const float*)d_in[2];
    const float* Wcell = (const float*)d_in[3];
    const float* bcell = (const float*)d_in[4];
    const float* Win   = (const float*)d_in[5];
    const float* bin   = (const float*)d_in[6];
    const float* Wih0  = (const float*)d_in[7];
    const float* Whh0  = (const float*)d_in[8];
    const float* bih0  = (const float*)d_in[9];
    const float* bhh0  = (const float*)d_in[10];
    const float* Wih1  = (const float*)d_in[11];
    const float* Whh1  = (const float*)d_in[12];
    const float* bih1  = (const float*)d_in[13];
    const float* bhh1  = (const float*)d_in[14];
    const float* Wout  = (const float*)d_in[15];
    const float* bout  = (const float*)d_in[16];
    float* out = (float*)d_out;

    // workspace: 2,101,248 B total (== round-8-proven size)
    u32*   gxb0u = (u32*)d_ws;                   // [131072] bf16-pair gate biases
    float* gxb1  = (float*)(gxb0u + 131072);     // [1024]
    float* c0    = gxb1 + 1024;                  // [65536]
    float* c1    = c0 + 65536;                   // [65536]
    u32*   hA0   = (u32*)(c1 + 65536);           // [65536] tagged u32 slots x4
    u32*   hA1   = hA0 + 65536;
    u32*   hB0   = hA1 + 65536;
    u32*   hB1   = hB0 + 65536;

    lstm_prologue_init<<<1028, 256, 0, stream>>>(z, Whid, bhid, Wcell, bcell,
                                                 bih1, bhh1, hA1, hB1, c0, c1, gxb1);
    lstm_prologue_gx0<<<dim3(2, 256), 256, 0, stream>>>(z, Win, bin, Wih0, bih0, bhh0, gxb0u);

    void* kargs[] = { (void*)&gxb0u, (void*)&gxb1, (void*)&c0, (void*)&c1,
                      (void*)&hA0, (void*)&hA1, (void*)&hB0, (void*)&hB1,
                      (void*)&Whh0, (void*)&Wih1, (void*)&Whh1, (void*)&Wout,
                      (void*)&bout, (void*)&out };
    hipError_t ce = hipLaunchCooperativeKernel((const void*)lstm_persistent,
                                               dim3(256), dim3(256), kargs, 0, stream);
    if (ce != hipSuccess) {
        lstm_persistent<<<256, 256, 0, stream>>>(gxb0u, gxb1, c0, c1,
                                                 hA0, hA1, hB0, hB1,
                                                 Whh0, Wih1, Whh1, Wout, bout, out);
    }
}

// Round 10
// 1562.533 us; speedup vs baseline: 3.6348x; 3.6348x over previous
//
#include <hip/hip_runtime.h>
#include <hip/hip_bf16.h>

#define LAT 128
#define H 256
#define OUTD 64
#define SEQ 512

typedef short bf16x8 __attribute__((ext_vector_type(8)));
typedef float f32x4  __attribute__((ext_vector_type(4)));
typedef unsigned long long u64;
typedef unsigned u32;

__device__ __forceinline__ float sigm(float x)  { return 1.f / (1.f + __expf(-x)); }
__device__ __forceinline__ float tanhf_(float x){ return 1.f - 2.f / (__expf(2.f * x) + 1.f); }

__device__ __forceinline__ short f2bs(float x) {
    __hip_bfloat16 b = __float2bfloat16(x);
    return *reinterpret_cast<short*>(&b);
}
__device__ __forceinline__ float bs2f(unsigned short h) {
    u32 b = ((u32)h) << 16;
    float f; __builtin_memcpy(&f, &b, 4); return f;
}
__device__ __forceinline__ u32 f2pair(float a, float b) {
    return ((u32)(unsigned short)f2bs(b) << 16) | (u32)(unsigned short)f2bs(a);
}
__device__ __forceinline__ bf16x8 pack8(const float* s) {
    bf16x8 v;
    v[0]=f2bs(s[0]); v[1]=f2bs(s[1]); v[2]=f2bs(s[2]); v[3]=f2bs(s[3]);
    v[4]=f2bs(s[4]); v[5]=f2bs(s[5]); v[6]=f2bs(s[6]); v[7]=f2bs(s[7]);
    return v;
}

// ---- LLC-coherent accessors (round-5/8-proven transport) ----
__device__ __forceinline__ u64 sys_load_u64(const u64* p) {
    return __hip_atomic_load((u64*)p, __ATOMIC_RELAXED, __HIP_MEMORY_SCOPE_SYSTEM);
}
__device__ __forceinline__ void sys_store_u64(u64* p, u64 v) {
    __hip_atomic_store(p, v, __ATOMIC_RELAXED, __HIP_MEMORY_SCOPE_SYSTEM);
}

// ---------------- Prologue 1 (round-8 verbatim): tagged h-init, c-init, L1 bias ----
// Tagged slot: u64 = (tag << 32) | (bf16[col+1] << 16) | bf16[col].
// h0 init -> h0B1 tag 0 (polled at iter 0); h1 init -> h1B1 tag 1 (iter 1).
__global__ void lstm_prologue_init(const float* __restrict__ z,
                                   const float* __restrict__ Whid,
                                   const float* __restrict__ bhid,
                                   const float* __restrict__ Wcell,
                                   const float* __restrict__ bcell,
                                   const float* __restrict__ bih1,
                                   const float* __restrict__ bhh1,
                                   u64* __restrict__ h0B1,
                                   u64* __restrict__ h1B1,
                                   float* __restrict__ c0,
                                   float* __restrict__ c1,
                                   float* __restrict__ gxb1)
{
    int t = blockIdx.x * 256 + threadIdx.x;
    if (t < 65536) {                     // tagged hidden-init: 2 layers x 256 b x 128 pairs
        int layer = t >> 15;
        int tt = t & 32767;
        int b = tt >> 7, cp = tt & 127;
        int colA = layer * H + 2 * cp;
        const float* zr = z + b * LAT;
        const float* wA = Whid + colA * LAT;
        const float* wB = wA + LAT;
        float a0 = bhid[colA], a1 = bhid[colA + 1];
        for (int k = 0; k < LAT; k++) { float zv = zr[k]; a0 += zv * wA[k]; a1 += zv * wB[k]; }
        u64 v = ((u64)(u32)layer << 32) | (u64)f2pair(a0, a1);
        (layer ? h1B1 : h0B1)[b * 128 + cp] = v;
    } else if (t < 196608) {             // cell init: [256 x 512]
        int tt = t - 65536;
        int b = tt >> 9, col = tt & 511;
        const float* w  = Wcell + col * LAT;
        const float* zr = z + b * LAT;
        float acc = bcell[col];
        for (int k = 0; k < LAT; k++) acc += zr[k] * w[k];
        if (col < H) c0[b * H + col] = acc;
        else         c1[b * H + (col - H)] = acc;
    } else if (t < 197632) {             // layer-1 gate bias vector [1024]
        int g = t - 196608;
        gxb1[g] = bih1[g] + bhh1[g];
    }
}

// ---------------- Prologue 2 (round-8 verbatim): gx0 packed bf16 pairs ----
__global__ void lstm_prologue_gx0(const float* __restrict__ z,
                                  const float* __restrict__ Win,
                                  const float* __restrict__ bin,
                                  const float* __restrict__ Wih0,
                                  const float* __restrict__ bih0,
                                  const float* __restrict__ bhh0,
                                  u32* __restrict__ gxb0u)
{
    __shared__ float xs[H];
    const int b = blockIdx.y;
    const int tid = threadIdx.x;
    {
        const float* w  = Win + tid * LAT;
        const float* zr = z + b * LAT;
        float acc = bin[tid];
        for (int k = 0; k < LAT; k++) acc += zr[k] * w[k];
        xs[tid] = acc;
    }
    __syncthreads();
    const int cA = blockIdx.x * 512 + 2 * tid;
    const float* wA = Wih0 + cA * H;
    const float* wB = wA + H;
    float a0 = bih0[cA]     + bhh0[cA];
    float a1 = bih0[cA + 1] + bhh0[cA + 1];
    for (int k = 0; k < H; k++) { float xv = xs[k]; a0 += xv * wA[k]; a1 += xv * wB[k]; }
    gxb0u[b * 512 + blockIdx.x * 256 + tid] = f2pair(a0, a1);
}

// ---------------- Persistent kernel ----------------
// 256 wgs x 256 thr. Cluster bg = wg>>4, wg j = wg&15 owns 16 hidden cols.
// Transposed MFMA: A = weight rows packed m = c*4+g, B = h rows. C lane (q,ln)
// reg r = gate r of (batch ln, col j*16+wave*4+q): nonlinearity on registers.
// Transport = round-8 u64 pair slots + tags. h0 staged at iteration TOP,
// h1 staged MID-iteration (max slack on both self-recurrences). Publishes via
// __shfl_xor(16) pack, even-q lanes store. Reload-all polls (one drain/spin).
__global__ __launch_bounds__(256, 1)
void lstm_persistent(const u32* __restrict__ gxb0u, const float* __restrict__ gxb1,
                     const float* __restrict__ c0g, const float* __restrict__ c1g,
                     u64* __restrict__ h0B0, u64* __restrict__ h0B1,
                     u64* __restrict__ h1B0, u64* __restrict__ h1B1,
                     const float* __restrict__ Whh0, const float* __restrict__ Wih1,
                     const float* __restrict__ Whh1, const float* __restrict__ Wout,
                     const float* __restrict__ bout, float* __restrict__ out)
{
    const int wg = blockIdx.x;
    const int bg = wg >> 4;
    const int j  = wg & 15;
    const int tid  = threadIdx.x;
    const int wave = tid >> 6;
    const int q  = (tid >> 4) & 3;
    const int ln = tid & 15;
    const int mycol = j * 16 + wave * 4 + q;
    const int myb   = bg * 16 + ln;

    __shared__ u32 hs0[2][16 * 132];           // parity planes, row-major packed pairs
    __shared__ u32 hs1[2][16 * 132];

    // ---- A-frags: packed-gate weight rows (m = c*4 + g) ----
    bf16x8 wf[3][8];
    {
        const float* mats[3] = { Whh0, Wih1, Whh1 };
        const int arow = (ln & 3) * H + j * 16 + wave * 4 + (ln >> 2);
        #pragma unroll
        for (int mm = 0; mm < 3; mm++) {
            const float* s = mats[mm] + arow * H;
            #pragma unroll
            for (int kk = 0; kk < 8; kk++) wf[mm][kk] = pack8(s + kk * 32 + q * 8);
        }
    }
    const bool doOut = (j < 4) && (wave == 0);
    bf16x8 wo[8];
    float bor[4] = {0.f, 0.f, 0.f, 0.f};
    if (doOut) {
        const int orow = j * 16 + ln;          // natural rows: C m = out-col
        const float* s = Wout + orow * H;
        #pragma unroll
        for (int kk = 0; kk < 8; kk++) wo[kk] = pack8(s + kk * 32 + q * 8);
        #pragma unroll
        for (int r = 0; r < 4; r++) bor[r] = bout[j * 16 + q * 4 + r];
    }

    // ---- per-lane gate biases + cell state ----
    float gxr0[4], gxr1[4];
    #pragma unroll
    for (int r = 0; r < 4; r++) {
        u32 v = gxb0u[myb * 512 + ((r * 256 + mycol) >> 1)];
        gxr0[r] = bs2f((unsigned short)((mycol & 1) ? (v >> 16) : (v & 0xFFFFu)));
        gxr1[r] = gxb1[r * 256 + mycol];
    }
    float creg0 = c0g[myb * H + mycol];
    float creg1 = c1g[myb * H + mycol];

    u64* A0 = h0B0 + bg * 2048;   // cluster slices: 16 rows x 128 pair-slots
    u64* A1 = h0B1 + bg * 2048;
    u64* B0 = h1B0 + bg * 2048;
    u64* B1 = h1B1 + bg * 2048;

    const int pubslot = ln * 128 + j * 8 + wave * 2 + (q >> 1);   // even-q lanes
    const bool pubLane = ((q & 1) == 0);

    for (int k = 0; k <= SEQ + 1; k++) {
        const u64* P0 = (k & 1) ? A0 : A1;  u64* C0 = (k & 1) ? A1 : A0;
        const u64* P1 = (k & 1) ? B1 : B0;  u64* C1 = (k & 1) ? B0 : B1;
        const int par = k & 1;

        // ---- TOP staging: h0 (reload-all poll; one drain per spin) ----
        if (k <= SEQ) {
            u64 v[8];
            bool ok = false; int guard = 0;
            while (!ok && guard < 16384) {
                ok = true;
                #pragma unroll
                for (int i = 0; i < 8; i++) v[i] = sys_load_u64(P0 + i * 256 + tid);
                #pragma unroll
                for (int i = 0; i < 8; i++) ok = ok && ((u32)(v[i] >> 32) == (u32)k);
                guard++;
            }
            u32* dst = hs0[par];
            #pragma unroll
            for (int i = 0; i < 8; i++) { int s = i * 256 + tid; dst[(s >> 7) * 132 + (s & 127)] = (u32)v[i]; }
        }
        __syncthreads();                       // B1

        // ---- h0 B-frags (batch row ln) ----
        bf16x8 hb0[8];
        {
            const unsigned short* b0p = (const unsigned short*)hs0[par];
            #pragma unroll
            for (int kk = 0; kk < 8; kk++)
                hb0[kk] = *(const bf16x8*)(b0p + ln * 264 + kk * 32 + q * 8);
        }

        // ---- layer 0, step k: gates in acc, publish from regs (early, ~0.4T) ----
        if (k < SEQ) {
            f32x4 acc = {0.f, 0.f, 0.f, 0.f};
            #pragma unroll
            for (int kk = 0; kk < 8; kk++)
                acc = __builtin_amdgcn_mfma_f32_16x16x32_bf16(wf[0][kk], hb0[kk], acc, 0, 0, 0);
            float i_ = sigm(acc[0] + gxr0[0]);
            float f_ = sigm(acc[1] + gxr0[1]);
            float g_ = tanhf_(acc[2] + gxr0[2]);
            float o_ = sigm(acc[3] + gxr0[3]);
            creg0 = f_ * creg0 + i_ * g_;
            int us = (int)(u32)(unsigned short)f2bs(o_ * tanhf_(creg0));
            int other = __shfl_xor(us, 16);    // q <-> q^1 (col pair partner)
            if (pubLane) {
                u32 pa = (u32)us | ((u32)other << 16);
                sys_store_u64(C0 + pubslot, ((u64)(u32)(k + 1) << 32) | (u64)pa);
            }
        }

        // ---- MID staging: h1 (published ~0.85T of prev iter -> ~0.6T slack) ----
        if (k >= 1) {
            u64 v[8];
            bool ok = false; int guard = 0;
            while (!ok && guard < 16384) {
                ok = true;
                #pragma unroll
                for (int i = 0; i < 8; i++) v[i] = sys_load_u64(P1 + i * 256 + tid);
                #pragma unroll
                for (int i = 0; i < 8; i++) ok = ok && ((u32)(v[i] >> 32) == (u32)k);
                guard++;
            }
            u32* dst = hs1[par];
            #pragma unroll
            for (int i = 0; i < 8; i++) { int s = i * 256 + tid; dst[(s >> 7) * 132 + (s & 127)] = (u32)v[i]; }
        }
        __syncthreads();                       // B2

        // ---- h1 B-frags ----
        bf16x8 hb1[8];
        {
            const unsigned short* b1p = (const unsigned short*)hs1[par];
            #pragma unroll
            for (int kk = 0; kk < 8; kk++)
                hb1[kk] = *(const bf16x8*)(b1p + ln * 264 + kk * 32 + q * 8);
        }

        // ---- layer 1, step k-1 ----
        if (k >= 1 && k <= SEQ) {
            f32x4 acc = {0.f, 0.f, 0.f, 0.f};
            #pragma unroll
            for (int kk = 0; kk < 8; kk++)
                acc = __builtin_amdgcn_mfma_f32_16x16x32_bf16(wf[1][kk], hb0[kk], acc, 0, 0, 0);
            #pragma unroll
            for (int kk = 0; kk < 8; kk++)
                acc = __builtin_amdgcn_mfma_f32_16x16x32_bf16(wf[2][kk], hb1[kk], acc, 0, 0, 0);
            float i_ = sigm(acc[0] + gxr1[0]);
            float f_ = sigm(acc[1] + gxr1[1]);
            float g_ = tanhf_(acc[2] + gxr1[2]);
            float o_ = sigm(acc[3] + gxr1[3]);
            creg1 = f_ * creg1 + i_ * g_;
            int us = (int)(u32)(unsigned short)f2bs(o_ * tanhf_(creg1));
            int other = __shfl_xor(us, 16);
            if (pubLane) {
                u32 pa = (u32)us | ((u32)other << 16);
                sys_store_u64(C1 + pubslot, ((u64)(u32)(k + 1) << 32) | (u64)pa);
            }
        }

        // ---- output projection, step k-2 (reuses hb1 = h1_{k-2}); f32x4 store ----
        if (k >= 2 && doOut) {
            f32x4 acc = {0.f, 0.f, 0.f, 0.f};
            #pragma unroll
            for (int kk = 0; kk < 8; kk++)
                acc = __builtin_amdgcn_mfma_f32_16x16x32_bf16(wo[kk], hb1[kk], acc, 0, 0, 0);
            f32x4 res;
            #pragma unroll
            for (int r = 0; r < 4; r++) res[r] = acc[r] + bor[r];
            *(f32x4*)&out[(bg * 16 + ln) * (SEQ * OUTD) + (k - 2) * OUTD + j * 16 + q * 4] = res;
        }
        // Plane safety: staging(k+1) writes parity par^1; writes to parity par
        // require passing B1/B2 of k+1, by which time all waves finished iter k.
    }
}

extern "C" void kernel_launch(void* const* d_in, const int* in_sizes, int n_in,
                              void* d_out, int out_size, void* d_ws, size_t ws_size,
                              hipStream_t stream) {
    const float* z     = (const float*)d_in[0];
    const float* Whid  = (const float*)d_in[1];
    const float* bhid  = (const float*)d_in[2];
    const float* Wcell = (const float*)d_in[3];
    const float* bcell = (const float*)d_in[4];
    const float* Win   = (const float*)d_in[5];
    const float* bin   = (const float*)d_in[6];
    const float* Wih0  = (const float*)d_in[7];
    const float* Whh0  = (const float*)d_in[8];
    const float* bih0  = (const float*)d_in[9];
    const float* bhh0  = (const float*)d_in[10];
    const float* Wih1  = (const float*)d_in[11];
    const float* Whh1  = (const float*)d_in[12];
    const float* bih1  = (const float*)d_in[13];
    const float* bhh1  = (const float*)d_in[14];
    const float* Wout  = (const float*)d_in[15];
    const float* bout  = (const float*)d_in[16];
    float* out = (float*)d_out;

    // workspace: 2,101,248 B total (== round-8-proven size)
    u32*   gxb0u = (u32*)d_ws;                   // [131072] bf16-pair gate biases
    float* gxb1  = (float*)(gxb0u + 131072);     // [1024]
    float* c0    = gxb1 + 1024;                  // [65536]
    float* c1    = c0 + 65536;                   // [65536]
    u64*   h0B0  = (u64*)(c1 + 65536);           // [32768] tagged pair-slots x4
    u64*   h0B1  = h0B0 + 32768;
    u64*   h1B0  = h0B1 + 32768;
    u64*   h1B1  = h1B0 + 32768;

    lstm_prologue_init<<<772, 256, 0, stream>>>(z, Whid, bhid, Wcell, bcell,
                                                bih1, bhh1, h0B1, h1B1, c0, c1, gxb1);
    lstm_prologue_gx0<<<dim3(2, 256), 256, 0, stream>>>(z, Win, bin, Wih0, bih0, bhh0, gxb0u);

    void* kargs[] = { (void*)&gxb0u, (void*)&gxb1, (void*)&c0, (void*)&c1,
                      (void*)&h0B0, (void*)&h0B1, (void*)&h1B0, (void*)&h1B1,
                      (void*)&Whh0, (void*)&Wih1, (void*)&Whh1, (void*)&Wout,
                      (void*)&bout, (void*)&out };
    hipError_t ce = hipLaunchCooperativeKernel((const void*)lstm_persistent,
                                               dim3(256), dim3(256), kargs, 0, stream);
    if (ce != hipSuccess) {
        lstm_persistent<<<256, 256, 0, stream>>>(gxb0u, gxb1, c0, c1,
                                                 h0B0, h0B1, h1B0, h1B1,
                                                 Whh0, Wih1, Whh1, Wout, bout, out);
    }
}